// Round 3
// baseline (266.257 us; speedup 1.0000x reference)
//
#include <hip/hip_runtime.h>
#include <math.h>

// SpatialSampler: B=256, A=64, k=64, P=32, BETA=0.1
// out = [places (33.55M f32) | sampled_points (33.55M f32)]
//   places[bp,j,k]  = h[bp,j] * v[bp,k]
//   sampled[bp,j,k] = 100*h[jmax]*v[kmax] at (jmax,kmax), else 0
//     jmax = argmax_j log(h[j]) + 0.1*noise_h[j]   (same for v/kmax)
//
// Strategy: hipMemsetAsync zeroes the sampled half (fill path measured at
// 6.5 TB/s on this chip), then one block per bp writes its 16 KB places tile
// with nontemporal dwordx4 stores + scatters the single nonzero sampled value.

#define BETA 0.1f
#define PLACES_ELEMS 33554432ull   // 256*32*64*64

typedef float vfloat4 __attribute__((ext_vector_type(4)));  // native vec for nt-store

__global__ __launch_bounds__(256) void places_argmax_kernel(
    const float* __restrict__ x_cat,
    const float* __restrict__ noise,
    float* __restrict__ out)
{
    const int bp   = blockIdx.x;       // b*32 + p, in [0, 8192)
    const int t    = threadIdx.x;
    const int wave = t >> 6;
    const int lane = t & 63;

    // x_cat[b, 2p+s, j] flat = bp*128 + s*64 + j
    const float* xrow = x_cat + (size_t)bp * 128;
    const float* nrow = noise + (size_t)bp * 128;

    __shared__ float sh[64];
    __shared__ float sv[64];
    __shared__ int   s_max[2];   // [0]=jmax, [1]=kmax

    if (wave < 2) {
        const int base = wave * 64 + lane;   // wave 0 -> h, wave 1 -> v
        float x = xrow[base];
        if (wave == 0) sh[lane] = x; else sv[lane] = x;

        float lp  = logf(x) + BETA * nrow[base];
        int   idx = lane;
        #pragma unroll
        for (int off = 32; off > 0; off >>= 1) {
            float o_lp  = __shfl_xor(lp, off, 64);
            int   o_idx = __shfl_xor(idx, off, 64);
            if (o_lp > lp || (o_lp == lp && o_idx < idx)) { lp = o_lp; idx = o_idx; }
        }
        if (lane == 0) s_max[wave] = idx;
    }
    __syncthreads();

    // places: float4 index f = i*256 + t in [0,1024).
    //   col-quad c = f & 15 = t & 15  (loop-invariant -> load v4 ONCE)
    //   row      j = f >> 4 = i*16 + (t >> 4)
    const int     c     = t & 15;
    const int     jbase = t >> 4;
    const vfloat4 v4    = ((const vfloat4*)sv)[c];  // ds_read_b128, 2-way alias (free)

    vfloat4* __restrict__ places = (vfloat4*)out + (size_t)bp * 1024;

    #pragma unroll
    for (int i = 0; i < 4; ++i) {
        const float hj = sh[i * 16 + jbase];        // 16-lane broadcast read
        vfloat4 p = hj * v4;
        __builtin_nontemporal_store(p, &places[i * 256 + t]);
    }

    // Scatter the one nonzero sampled value (memset already zeroed the rest).
    if (t == 0) {
        const int jmax = s_max[0];
        const int kmax = s_max[1];
        out[PLACES_ELEMS + (size_t)bp * 4096 + (size_t)(jmax * 64 + kmax)] =
            100.0f * sh[jmax] * sv[kmax];
    }
}

extern "C" void kernel_launch(void* const* d_in, const int* in_sizes, int n_in,
                              void* d_out, int out_size, void* d_ws, size_t ws_size,
                              hipStream_t stream) {
    const float* x_cat = (const float*)d_in[0];
    const float* noise = (const float*)d_in[1];
    float* out = (float*)d_out;

    // Zero the sampled_points half via the fast fill path (~6.5 TB/s measured).
    (void)hipMemsetAsync((void*)(out + PLACES_ELEMS), 0,
                         PLACES_ELEMS * sizeof(float), stream);

    // One block per (b,p) pair: writes 16 KB of places + 1 scatter store.
    places_argmax_kernel<<<dim3(8192), dim3(256), 0, stream>>>(x_cat, noise, out);
}

// Round 4
// 242.144 us; speedup vs baseline: 1.0996x; 1.0996x over previous
//
#include <hip/hip_runtime.h>
#include <math.h>

// SpatialSampler: B=256, A=64, k=64, P=32, BETA=0.1
// out = [places (33.55M f32) | sampled_points (33.55M f32)]
//   places[bp,j,k]  = h[bp,j] * v[bp,k]
//   sampled[bp,j,k] = 100*h[jmax]*v[kmax] at (jmax,kmax), else 0
//
// K1: pure streaming writer (fill-kernel-shaped: no LDS, no barrier, low VGPR).
//     Writes places (computed from L1/L2-cached 4MB x_cat) and zeros for the
//     sampled half. 268 MB of coalesced float4 stores.
// K2: one wave per bp, in-wave shuffle argmax (no LDS/barrier), lane 0
//     overwrites the single nonzero sampled element. Runs after K1.

#define BETA 0.1f
#define PLACES_ELEMS 33554432ull     // 256*32*64*64
#define TOTAL_F4     8388608         // 2*PLACES_ELEMS/4
#define K1_THREADS   2097152         // 8192 blocks * 256; 4 f4-stores per thread

typedef float vfloat4 __attribute__((ext_vector_type(4)));

__global__ __launch_bounds__(256) void k1_stream(
    const float* __restrict__ x_cat,
    float* __restrict__ out)
{
    const int gid = blockIdx.x * 256 + threadIdx.x;   // [0, 2097152)
    vfloat4* __restrict__ out4 = (vfloat4*)out;

    #pragma unroll
    for (int k = 0; k < 4; ++k) {
        const int u = gid + k * K1_THREADS;           // f4 index in [0, 8388608)
        vfloat4 val;
        if (k < 2) {
            // places half: u < 4194304
            const int bp = u >> 10;                   // (b,p) pair
            const int f  = u & 1023;                  // f4 within tile
            const int j  = f >> 4;                    // row 0..63
            const int c  = f & 15;                    // col quad 0..15
            const float* base = x_cat + (size_t)bp * 128;
            const float  h    = base[j];              // L1-broadcast
            const vfloat4 v4  = *(const vfloat4*)(base + 64 + 4 * c);
            val = h * v4;
        } else {
            val = (vfloat4){0.f, 0.f, 0.f, 0.f};      // sampled half: zeros
        }
        out4[u] = val;                                // coalesced dwordx4
    }
}

__global__ __launch_bounds__(256) void k2_argmax_scatter(
    const float* __restrict__ x_cat,
    const float* __restrict__ noise,
    float* __restrict__ out)
{
    const int wid  = blockIdx.x * 4 + (threadIdx.x >> 6);  // wave id = bp, [0,8192)
    const int lane = threadIdx.x & 63;

    const float* xrow = x_cat + (size_t)wid * 128;
    const float* nrow = noise + (size_t)wid * 128;

    const float h  = xrow[lane];
    const float v  = xrow[64 + lane];
    float lph = logf(h) + BETA * nrow[lane];
    float lpv = logf(v) + BETA * nrow[64 + lane];
    int   jh  = lane;
    int   jv  = lane;

    #pragma unroll
    for (int off = 32; off > 0; off >>= 1) {
        const float oh = __shfl_xor(lph, off, 64);
        const int   oi = __shfl_xor(jh,  off, 64);
        const float ov = __shfl_xor(lpv, off, 64);
        const int   oj = __shfl_xor(jv,  off, 64);
        if (oh > lph || (oh == lph && oi < jh)) { lph = oh; jh = oi; }
        if (ov > lpv || (ov == lpv && oj < jv)) { lpv = ov; jv = oj; }
    }
    // jh/jv now wave-uniform argmax indices
    const float hmax = __shfl(h, jh, 64);
    const float vmax = __shfl(v, jv, 64);
    if (lane == 0) {
        out[PLACES_ELEMS + (size_t)wid * 4096 + (size_t)(jh * 64 + jv)] =
            100.0f * hmax * vmax;
    }
}

extern "C" void kernel_launch(void* const* d_in, const int* in_sizes, int n_in,
                              void* d_out, int out_size, void* d_ws, size_t ws_size,
                              hipStream_t stream) {
    const float* x_cat = (const float*)d_in[0];
    const float* noise = (const float*)d_in[1];
    float* out = (float*)d_out;

    // K1: 8192 blocks x 256 threads, 4 float4 stores each = full 268 MB output.
    k1_stream<<<dim3(8192), dim3(256), 0, stream>>>(x_cat, out);

    // K2: 8192 waves (one per bp) = 2048 blocks x 256; scatters 8192 values.
    k2_argmax_scatter<<<dim3(2048), dim3(256), 0, stream>>>(x_cat, noise, out);
}